// Round 1
// baseline (365.712 us; speedup 1.0000x reference)
//
#include <hip/hip_runtime.h>
#include <hip/hip_bf16.h>

typedef __attribute__((ext_vector_type(8))) short bf16x8;
typedef __attribute__((ext_vector_type(4))) float f32x4;
typedef unsigned short u16;

__device__ __forceinline__ u16 f2bf(float f) {
  unsigned u = __float_as_uint(f);
  u += 0x7fffu + ((u >> 16) & 1u);
  return (u16)(u >> 16);
}

__device__ __forceinline__ void gload16(const void* g, void* l) {
  __builtin_amdgcn_global_load_lds(
      (const __attribute__((address_space(1))) unsigned int*)g,
      (__attribute__((address_space(3))) unsigned int*)l, 16, 0, 0);
}

// ---------------- rope tables: cos(sin(s*freq)), sin(sin(s*freq)) ----------
__global__ __launch_bounds__(256) void rope_tables_kernel(float* cosT, float* sinT) {
  int i = blockIdx.x * 256 + threadIdx.x;
  if (i >= 1024 * 32) return;
  int s = i >> 5, p = i & 31;
  double freq = exp(-9.210340371976184 * (double)(2 * p) / 64.0);
  double ang = sin((double)s * freq);
  cosT[i] = (float)cos(ang);
  sinT[i] = (float)sin(ang);
}

// ---------------- f32 -> bf16 convert (vectorized) -------------------------
__global__ __launch_bounds__(256) void tobf16_kernel(const float* __restrict__ in,
                                                     u16* __restrict__ out) {
  size_t i = ((size_t)blockIdx.x * 256 + threadIdx.x) * 4;
  float4 v = *(const float4*)(in + i);
  u16 a = f2bf(v.x), b = f2bf(v.y), c = f2bf(v.z), d = f2bf(v.w);
  ushort4 o = make_ushort4(a, b, c, d);
  *(ushort4*)(out + i) = o;
}

// ---------------- W (1024x1024 f32, row=k) -> Wt (row=n) bf16 --------------
__global__ __launch_bounds__(256) void wtrans_kernel(const float* __restrict__ W,
                                                     u16* __restrict__ Wt) {
  __shared__ float tile[32][33];
  int tx = threadIdx.x & 31, ty = threadIdx.x >> 5;
  int k0 = blockIdx.y * 32, n0 = blockIdx.x * 32;
#pragma unroll
  for (int i = 0; i < 4; ++i)
    tile[ty + i * 8][tx] = W[(size_t)(k0 + ty + i * 8) * 1024 + n0 + tx];
  __syncthreads();
#pragma unroll
  for (int i = 0; i < 4; ++i)
    Wt[(size_t)(n0 + ty + i * 8) * 1024 + k0 + tx] = f2bf(tile[tx][ty + i * 8]);
}

// ---------------- vb (b,s,h,d) bf16 -> vt (b,h,d,s) bf16 -------------------
__global__ __launch_bounds__(256) void vtrans_kernel(const u16* __restrict__ vb,
                                                     u16* __restrict__ vt) {
  __shared__ u16 tile[64][72];
  int z = blockIdx.y, b = z >> 4, h = z & 15;
  int s0 = blockIdx.x * 64;
  int t = threadIdx.x;
#pragma unroll
  for (int it = 0; it < 2; ++it) {
    int idx = t + it * 256;
    int s = idx >> 3, d = (idx & 7) * 8;
    bf16x8 v = *(const bf16x8*)(vb + ((size_t)(b * 1024 + s0 + s) * 1024 + h * 64 + d));
    *(bf16x8*)&tile[s][d] = v;
  }
  __syncthreads();
#pragma unroll
  for (int it = 0; it < 2; ++it) {
    int idx = t + it * 256;
    int d = idx >> 3, sc = (idx & 7) * 8;
    bf16x8 o;
#pragma unroll
    for (int i = 0; i < 8; ++i) o[i] = (short)tile[sc + i][d];
    *(bf16x8*)(vt + ((size_t)(z * 64 + d)) * 1024 + s0 + sc) = o;
  }
}

// ---------------- 128x128-tile bf16 GEMM: C = A(MxK) * Bt(NxK)^T + bias ----
// EPI 0: RoPE -> bf16 out; EPI 1: bf16 out; EPI 2: f32 out
template <int EPI>
__global__ __launch_bounds__(256) void gemm_bias(
    const u16* __restrict__ A, const u16* __restrict__ Bt,
    const float* __restrict__ bias, void* __restrict__ Cout,
    const float* __restrict__ cosT, const float* __restrict__ sinT,
    int M, int N, int K) {
  __shared__ u16 lA[128 * 32];
  __shared__ u16 lB[128 * 32];
  const int tid = threadIdx.x;
  const int lane = tid & 63, wid = tid >> 6;
  const int wm = wid >> 1, wn = wid & 1;
  const int lr = lane & 15, kg = lane >> 4;
  const int m0 = blockIdx.y * 128, n0 = blockIdx.x * 128;

  f32x4 acc[4][4] = {};
  for (int k0 = 0; k0 < K; k0 += 32) {
#pragma unroll
    for (int it = 0; it < 2; ++it) {
      int o = tid * 16 + it * 4096;
      int row = o >> 6;
      int cbs = (((o >> 4) & 3) ^ (row & 3)) << 4;  // chunk swizzle
      gload16((const char*)A + ((size_t)(m0 + row) * K + k0) * 2 + cbs, (char*)lA + o);
      gload16((const char*)Bt + ((size_t)(n0 + row) * K + k0) * 2 + cbs, (char*)lB + o);
    }
    __syncthreads();
    bf16x8 av[4], bv[4];
#pragma unroll
    for (int i = 0; i < 4; ++i) {
      int ra = wm * 64 + i * 16 + lr;
      av[i] = *(const bf16x8*)((const char*)lA + ra * 64 + ((kg ^ (ra & 3)) << 4));
      int rb = wn * 64 + i * 16 + lr;
      bv[i] = *(const bf16x8*)((const char*)lB + rb * 64 + ((kg ^ (rb & 3)) << 4));
    }
#pragma unroll
    for (int i = 0; i < 4; ++i)
#pragma unroll
      for (int j = 0; j < 4; ++j)
        acc[i][j] = __builtin_amdgcn_mfma_f32_16x16x32_bf16(av[i], bv[j], acc[i][j], 0, 0, 0);
    __syncthreads();
  }
#pragma unroll
  for (int i = 0; i < 4; ++i) {
#pragma unroll
    for (int j = 0; j < 4; ++j) {
      int col = n0 + wn * 64 + j * 16 + lr;
      float bcol = bias[col];
#pragma unroll
      for (int r = 0; r < 4; ++r) {
        int row = m0 + wm * 64 + i * 16 + kg * 4 + r;
        float v = acc[i][j][r] + bcol;
        if constexpr (EPI == 2) {
          ((float*)Cout)[(size_t)row * N + col] = v;
        } else if constexpr (EPI == 1) {
          ((u16*)Cout)[(size_t)row * N + col] = f2bf(v);
        } else {
          float pv = __shfl_xor(v, 1);
          int p = (col & 63) >> 1;
          int s = row & 1023;
          float ct = cosT[s * 32 + p], st = sinT[s * 32 + p];
          float ov = (col & 1) ? (v * ct + pv * st) : (v * ct - pv * st);
          ((u16*)Cout)[(size_t)row * N + col] = f2bf(ov);
        }
      }
    }
  }
}

// ---------------- scores = (1/8) * Qh * Kh^T  (K=64, per (b,h)) -------------
__global__ __launch_bounds__(256) void scores_kernel(const u16* __restrict__ qr,
                                                     const u16* __restrict__ kr,
                                                     float* __restrict__ probs) {
  __shared__ u16 lA[128 * 64];
  __shared__ u16 lB[128 * 64];
  const int tid = threadIdx.x;
  const int lane = tid & 63, wid = tid >> 6;
  const int wm = wid >> 1, wn = wid & 1;
  const int lr = lane & 15, kg = lane >> 4;
  const int z = blockIdx.z, b = z >> 4, h = z & 15;
  const int m0 = blockIdx.y * 128, n0 = blockIdx.x * 128;
  const u16* Ab = qr + (size_t)b * 1024 * 1024 + h * 64;
  const u16* Bb = kr + (size_t)b * 1024 * 1024 + h * 64;
  float* C = probs + (size_t)z * 1024 * 1024;

#pragma unroll
  for (int it = 0; it < 4; ++it) {
    int o = tid * 16 + it * 4096;
    int row = o >> 7;
    int cbs = (((o >> 4) & 7) ^ (row & 7)) << 4;
    gload16((const char*)Ab + (size_t)(m0 + row) * 2048 + cbs, (char*)lA + o);
    gload16((const char*)Bb + (size_t)(n0 + row) * 2048 + cbs, (char*)lB + o);
  }
  __syncthreads();
  f32x4 acc[4][4] = {};
#pragma unroll
  for (int kk = 0; kk < 2; ++kk) {
    bf16x8 av[4], bv[4];
#pragma unroll
    for (int i = 0; i < 4; ++i) {
      int ra = wm * 64 + i * 16 + lr;
      av[i] = *(const bf16x8*)((const char*)lA + ra * 128 + ((((kk << 2) | kg) ^ (ra & 7)) << 4));
      int rb = wn * 64 + i * 16 + lr;
      bv[i] = *(const bf16x8*)((const char*)lB + rb * 128 + ((((kk << 2) | kg) ^ (rb & 7)) << 4));
    }
#pragma unroll
    for (int i = 0; i < 4; ++i)
#pragma unroll
      for (int j = 0; j < 4; ++j)
        acc[i][j] = __builtin_amdgcn_mfma_f32_16x16x32_bf16(av[i], bv[j], acc[i][j], 0, 0, 0);
  }
#pragma unroll
  for (int i = 0; i < 4; ++i)
#pragma unroll
    for (int j = 0; j < 4; ++j) {
      int col = n0 + wn * 64 + j * 16 + lr;
#pragma unroll
      for (int r = 0; r < 4; ++r) {
        int row = m0 + wm * 64 + i * 16 + kg * 4 + r;
        C[(size_t)row * 1024 + col] = acc[i][j][r] * 0.125f;
      }
    }
}

// ---------------- row softmax, in place (one block per row) ----------------
__global__ __launch_bounds__(256) void softmax_kernel(float* __restrict__ probs) {
  const size_t row = blockIdx.x;
  float* p = probs + row * 1024;
  const int t = threadIdx.x;
  float4 v = *(float4*)(p + t * 4);
  float m = fmaxf(fmaxf(v.x, v.y), fmaxf(v.z, v.w));
#pragma unroll
  for (int off = 32; off > 0; off >>= 1) m = fmaxf(m, __shfl_xor(m, off));
  __shared__ float red[8];
  int wid = t >> 6, lane = t & 63;
  if (lane == 0) red[wid] = m;
  __syncthreads();
  m = fmaxf(fmaxf(red[0], red[1]), fmaxf(red[2], red[3]));
  v.x = __expf(v.x - m); v.y = __expf(v.y - m);
  v.z = __expf(v.z - m); v.w = __expf(v.w - m);
  float s = v.x + v.y + v.z + v.w;
#pragma unroll
  for (int off = 32; off > 0; off >>= 1) s += __shfl_xor(s, off);
  if (lane == 0) red[4 + wid] = s;
  __syncthreads();
  s = red[4] + red[5] + red[6] + red[7];
  float inv = 1.0f / s;
  v.x *= inv; v.y *= inv; v.z *= inv; v.w *= inv;
  *(float4*)(p + t * 4) = v;
}

// ---------------- ctx = probs(f32) @ V  via vt (b,h,d,s) -------------------
__global__ __launch_bounds__(256) void pv_kernel(const float* __restrict__ probs,
                                                 const u16* __restrict__ vt,
                                                 u16* __restrict__ ctx) {
  __shared__ float lP[128 * 32];
  __shared__ u16 lV[64 * 32];
  const int tid = threadIdx.x;
  const int lane = tid & 63, wid = tid >> 6;
  const int lr = lane & 15, kg = lane >> 4;
  const int z = blockIdx.z, b = z >> 4, h = z & 15;
  const int m0 = blockIdx.x * 128;
  const float* P = probs + (size_t)z * 1024 * 1024;
  const u16* V = vt + (size_t)z * 64 * 1024;

  f32x4 acc[2][4] = {};
  for (int t0 = 0; t0 < 1024; t0 += 32) {
#pragma unroll
    for (int it = 0; it < 4; ++it) {
      int o = tid * 16 + it * 4096;
      int row = o >> 7;
      int cbs = (((o >> 4) & 7) ^ (row & 7)) << 4;
      gload16((const char*)P + (size_t)(m0 + row) * 4096 + t0 * 4 + cbs, (char*)lP + o);
    }
    {
      int o = tid * 16;
      int row = o >> 6;
      int cbs = (((o >> 4) & 3) ^ (row & 3)) << 4;
      gload16((const char*)V + (size_t)row * 2048 + t0 * 2 + cbs, (char*)lV + o);
    }
    __syncthreads();
    bf16x8 av[2];
#pragma unroll
    for (int i = 0; i < 2; ++i) {
      int ra = wid * 32 + i * 16 + lr;
      const char* base = (const char*)lP + ra * 128;
      f32x4 x0 = *(const f32x4*)(base + ((((kg << 1) | 0) ^ (ra & 7)) << 4));
      f32x4 x1 = *(const f32x4*)(base + ((((kg << 1) | 1) ^ (ra & 7)) << 4));
      bf16x8 tmp;
      tmp[0] = (short)f2bf(x0[0]); tmp[1] = (short)f2bf(x0[1]);
      tmp[2] = (short)f2bf(x0[2]); tmp[3] = (short)f2bf(x0[3]);
      tmp[4] = (short)f2bf(x1[0]); tmp[5] = (short)f2bf(x1[1]);
      tmp[6] = (short)f2bf(x1[2]); tmp[7] = (short)f2bf(x1[3]);
      av[i] = tmp;
    }
    bf16x8 bv[4];
#pragma unroll
    for (int j = 0; j < 4; ++j) {
      int rb = j * 16 + lr;
      bv[j] = *(const bf16x8*)((const char*)lV + rb * 64 + ((kg ^ (rb & 3)) << 4));
    }
#pragma unroll
    for (int i = 0; i < 2; ++i)
#pragma unroll
      for (int j = 0; j < 4; ++j)
        acc[i][j] = __builtin_amdgcn_mfma_f32_16x16x32_bf16(av[i], bv[j], acc[i][j], 0, 0, 0);
    __syncthreads();
  }
#pragma unroll
  for (int i = 0; i < 2; ++i)
#pragma unroll
    for (int j = 0; j < 4; ++j)
#pragma unroll
      for (int r = 0; r < 4; ++r) {
        int srow = m0 + wid * 32 + i * 16 + kg * 4 + r;
        int d = j * 16 + lr;
        ctx[((size_t)(b * 1024 + srow)) * 1024 + h * 64 + d] = f2bf(acc[i][j][r]);
      }
}

// ---------------------------------------------------------------------------
extern "C" void kernel_launch(void* const* d_in, const int* in_sizes, int n_in,
                              void* d_out, int out_size, void* d_ws, size_t ws_size,
                              hipStream_t stream) {
  const float* query = (const float*)d_in[0];
  const float* key_ = (const float*)d_in[1];
  const float* value = (const float*)d_in[2];
  const float* Wq = (const float*)d_in[3];
  const float* bq = (const float*)d_in[4];
  const float* Wk = (const float*)d_in[5];
  const float* bk = (const float*)d_in[6];
  const float* Wv = (const float*)d_in[7];
  const float* bv = (const float*)d_in[8];
  const float* Wo = (const float*)d_in[9];
  const float* bo = (const float*)d_in[10];

  float* out = (float*)d_out;
  float* probs = out + (size_t)4 * 1024 * 1024;

  char* w = (char*)d_ws;
  const size_t SZ_MK = (size_t)4096 * 1024 * 2;  // 8 MB bf16
  const size_t SZ_W = (size_t)1024 * 1024 * 2;   // 2 MB bf16
  u16* qin = (u16*)w; w += SZ_MK;
  u16* kin = (u16*)w; w += SZ_MK;
  u16* vin = (u16*)w; w += SZ_MK;
  u16* qr = (u16*)w; w += SZ_MK;
  u16* kr = (u16*)w; w += SZ_MK;
  u16* vb = (u16*)w; w += SZ_MK;
  u16* WqT = (u16*)w; w += SZ_W;
  u16* WkT = (u16*)w; w += SZ_W;
  u16* WvT = (u16*)w; w += SZ_W;
  u16* WoT = (u16*)w; w += SZ_W;
  float* cosT = (float*)w; w += 1024 * 32 * 4;
  float* sinT = (float*)w; w += 1024 * 32 * 4;
  // aliases (lifetimes do not overlap):
  u16* vt = kin;   // kin dead after k-projection; vt written afterwards
  u16* ctx = qin;  // qin dead after q-projection; ctx written by pv

  dim3 blk(256);
  hipLaunchKernelGGL(rope_tables_kernel, dim3(128), blk, 0, stream, cosT, sinT);
  hipLaunchKernelGGL(tobf16_kernel, dim3(4096), blk, 0, stream, query, qin);
  hipLaunchKernelGGL(tobf16_kernel, dim3(4096), blk, 0, stream, key_, kin);
  hipLaunchKernelGGL(tobf16_kernel, dim3(4096), blk, 0, stream, value, vin);
  dim3 wg(32, 32);
  hipLaunchKernelGGL(wtrans_kernel, wg, blk, 0, stream, Wq, WqT);
  hipLaunchKernelGGL(wtrans_kernel, wg, blk, 0, stream, Wk, WkT);
  hipLaunchKernelGGL(wtrans_kernel, wg, blk, 0, stream, Wv, WvT);
  hipLaunchKernelGGL(wtrans_kernel, wg, blk, 0, stream, Wo, WoT);

  dim3 pg(8, 32);
  hipLaunchKernelGGL(HIP_KERNEL_NAME(gemm_bias<0>), pg, blk, 0, stream,
                     qin, WqT, bq, (void*)qr, cosT, sinT, 4096, 1024, 1024);
  hipLaunchKernelGGL(HIP_KERNEL_NAME(gemm_bias<0>), pg, blk, 0, stream,
                     kin, WkT, bk, (void*)kr, cosT, sinT, 4096, 1024, 1024);
  hipLaunchKernelGGL(HIP_KERNEL_NAME(gemm_bias<1>), pg, blk, 0, stream,
                     vin, WvT, bv, (void*)vb, cosT, sinT, 4096, 1024, 1024);
  hipLaunchKernelGGL(vtrans_kernel, dim3(16, 64), blk, 0, stream, vb, vt);

  hipLaunchKernelGGL(scores_kernel, dim3(8, 8, 64), blk, 0, stream, qr, kr, probs);
  hipLaunchKernelGGL(softmax_kernel, dim3(65536), blk, 0, stream, probs);
  hipLaunchKernelGGL(pv_kernel, dim3(8, 1, 64), blk, 0, stream, probs, vt, ctx);
  hipLaunchKernelGGL(HIP_KERNEL_NAME(gemm_bias<2>), pg, blk, 0, stream,
                     ctx, WoT, bo, (void*)out, cosT, sinT, 4096, 1024, 1024);
}

// Round 2
// 242.346 us; speedup vs baseline: 1.5090x; 1.5090x over previous
//
#include <hip/hip_runtime.h>
#include <hip/hip_bf16.h>

typedef __attribute__((ext_vector_type(8))) short bf16x8;
typedef __attribute__((ext_vector_type(4))) float f32x4;
typedef unsigned short u16;

__device__ __forceinline__ u16 f2bf(float f) {
  unsigned u = __float_as_uint(f);
  u += 0x7fffu + ((u >> 16) & 1u);
  return (u16)(u >> 16);
}

__device__ __forceinline__ void gload16(const void* g, void* l) {
  __builtin_amdgcn_global_load_lds(
      (const __attribute__((address_space(1))) unsigned int*)g,
      (__attribute__((address_space(3))) unsigned int*)l, 16, 0, 0);
}

// ---------------- rope tables: cos(sin(s*freq)), sin(sin(s*freq)) ----------
__global__ __launch_bounds__(256) void rope_tables_kernel(float* cosT, float* sinT) {
  int i = blockIdx.x * 256 + threadIdx.x;
  if (i >= 1024 * 32) return;
  int s = i >> 5, p = i & 31;
  double freq = exp(-9.210340371976184 * (double)(2 * p) / 64.0);
  double ang = sin((double)s * freq);
  cosT[i] = (float)cos(ang);
  sinT[i] = (float)sin(ang);
}

// ---------------- f32 -> bf16 convert (vectorized) -------------------------
__global__ __launch_bounds__(256) void tobf16_kernel(const float* __restrict__ in,
                                                     u16* __restrict__ out) {
  size_t i = ((size_t)blockIdx.x * 256 + threadIdx.x) * 4;
  float4 v = *(const float4*)(in + i);
  u16 a = f2bf(v.x), b = f2bf(v.y), c = f2bf(v.z), d = f2bf(v.w);
  ushort4 o = make_ushort4(a, b, c, d);
  *(ushort4*)(out + i) = o;
}

// ---------------- W (1024x1024 f32, row=k) -> Wt (row=n) bf16 --------------
__global__ __launch_bounds__(256) void wtrans_kernel(const float* __restrict__ W,
                                                     u16* __restrict__ Wt) {
  __shared__ float tile[32][33];
  int tx = threadIdx.x & 31, ty = threadIdx.x >> 5;
  int k0 = blockIdx.y * 32, n0 = blockIdx.x * 32;
#pragma unroll
  for (int i = 0; i < 4; ++i)
    tile[ty + i * 8][tx] = W[(size_t)(k0 + ty + i * 8) * 1024 + n0 + tx];
  __syncthreads();
#pragma unroll
  for (int i = 0; i < 4; ++i)
    Wt[(size_t)(n0 + ty + i * 8) * 1024 + k0 + tx] = f2bf(tile[tx][ty + i * 8]);
}

// ---------------- vb (b,s,h,d) bf16 -> vt (b,h,d,s) bf16 -------------------
__global__ __launch_bounds__(256) void vtrans_kernel(const u16* __restrict__ vb,
                                                     u16* __restrict__ vt) {
  __shared__ u16 tile[64][72];
  int z = blockIdx.y, b = z >> 4, h = z & 15;
  int s0 = blockIdx.x * 64;
  int t = threadIdx.x;
#pragma unroll
  for (int it = 0; it < 2; ++it) {
    int idx = t + it * 256;
    int s = idx >> 3, d = (idx & 7) * 8;
    bf16x8 v = *(const bf16x8*)(vb + ((size_t)(b * 1024 + s0 + s) * 1024 + h * 64 + d));
    *(bf16x8*)&tile[s][d] = v;
  }
  __syncthreads();
#pragma unroll
  for (int it = 0; it < 2; ++it) {
    int idx = t + it * 256;
    int d = idx >> 3, sc = (idx & 7) * 8;
    bf16x8 o;
#pragma unroll
    for (int i = 0; i < 8; ++i) o[i] = (short)tile[sc + i][d];
    *(bf16x8*)(vt + ((size_t)(z * 64 + d)) * 1024 + s0 + sc) = o;
  }
}

// ---------------- 128x128-tile bf16 GEMM: C = A(MxK) * Bt(NxK)^T + bias ----
// EPI 0: RoPE -> bf16 out; EPI 1: bf16 out; EPI 2: f32 out
template <int EPI>
__global__ __launch_bounds__(256) void gemm_bias(
    const u16* __restrict__ A, const u16* __restrict__ Bt,
    const float* __restrict__ bias, void* __restrict__ Cout,
    const float* __restrict__ cosT, const float* __restrict__ sinT,
    int M, int N, int K) {
  __shared__ u16 lA[128 * 32];
  __shared__ u16 lB[128 * 32];
  const int tid = threadIdx.x;
  const int lane = tid & 63, wid = tid >> 6;
  const int wm = wid >> 1, wn = wid & 1;
  const int lr = lane & 15, kg = lane >> 4;
  const int m0 = blockIdx.y * 128, n0 = blockIdx.x * 128;

  f32x4 acc[4][4] = {};
  for (int k0 = 0; k0 < K; k0 += 32) {
#pragma unroll
    for (int it = 0; it < 2; ++it) {
      int o = tid * 16 + it * 4096;
      int row = o >> 6;
      int cbs = (((o >> 4) & 3) ^ (row & 3)) << 4;  // chunk swizzle
      gload16((const char*)A + ((size_t)(m0 + row) * K + k0) * 2 + cbs, (char*)lA + o);
      gload16((const char*)Bt + ((size_t)(n0 + row) * K + k0) * 2 + cbs, (char*)lB + o);
    }
    __syncthreads();
    bf16x8 av[4], bv[4];
#pragma unroll
    for (int i = 0; i < 4; ++i) {
      int ra = wm * 64 + i * 16 + lr;
      av[i] = *(const bf16x8*)((const char*)lA + ra * 64 + ((kg ^ (ra & 3)) << 4));
      int rb = wn * 64 + i * 16 + lr;
      bv[i] = *(const bf16x8*)((const char*)lB + rb * 64 + ((kg ^ (rb & 3)) << 4));
    }
#pragma unroll
    for (int i = 0; i < 4; ++i)
#pragma unroll
      for (int j = 0; j < 4; ++j)
        acc[i][j] = __builtin_amdgcn_mfma_f32_16x16x32_bf16(av[i], bv[j], acc[i][j], 0, 0, 0);
    __syncthreads();
  }
#pragma unroll
  for (int i = 0; i < 4; ++i) {
#pragma unroll
    for (int j = 0; j < 4; ++j) {
      int col = n0 + wn * 64 + j * 16 + lr;
      float bcol = bias[col];
#pragma unroll
      for (int r = 0; r < 4; ++r) {
        int row = m0 + wm * 64 + i * 16 + kg * 4 + r;
        float v = acc[i][j][r] + bcol;
        if constexpr (EPI == 2) {
          ((float*)Cout)[(size_t)row * N + col] = v;
        } else if constexpr (EPI == 1) {
          ((u16*)Cout)[(size_t)row * N + col] = f2bf(v);
        } else {
          float pv = __shfl_xor(v, 1);
          int p = (col & 63) >> 1;
          int s = row & 1023;
          float ct = cosT[s * 32 + p], st = sinT[s * 32 + p];
          float ov = (col & 1) ? (v * ct + pv * st) : (v * ct - pv * st);
          ((u16*)Cout)[(size_t)row * N + col] = f2bf(ov);
        }
      }
    }
  }
}

// ---------------- fused scores + softmax + PV ------------------------------
// Block: 256 threads (4 waves), owns 32 q-rows of one (b,h).
// Phase 1: accS[8][2][2] = full 32x1024 scaled scores (wave w owns cols
//          c*128 + w*32 + jj*16 + lr).
// Phase 2: row softmax (16-lane shfl groups + cross-wave LDS combine).
// Phase 3: per kv-chunk: write probs f32 global + P bf16 -> swizzled LDS,
//          stage V chunk, MFMA accumulate ctx (wave quadrant 16 rows x 32 d).
__global__ __launch_bounds__(256, 2) void fused_attn_kernel(
    const u16* __restrict__ qr, const u16* __restrict__ kr,
    const u16* __restrict__ vt, float* __restrict__ probs,
    u16* __restrict__ ctx) {
  __shared__ u16 lQ[32 * 64];
  __shared__ u16 lK[2][128 * 64];
  __shared__ u16 lV[2][64 * 128];
  __shared__ u16 lP[32 * 128];
  __shared__ float redM[4][32];
  __shared__ float redS[4][32];

  const int tid = threadIdx.x;
  const int lane = tid & 63, wid = tid >> 6;
  const int lr = lane & 15, kg = lane >> 4;
  const int z = blockIdx.y, b = z >> 4, h = z & 15;
  const int m0 = blockIdx.x * 32;

  const char* Qb = (const char*)qr + ((size_t)(b * 1024 + m0) * 1024 + h * 64) * 2;
  const char* Kb = (const char*)kr + ((size_t)(b * 1024) * 1024 + h * 64) * 2;
  const char* Vb = (const char*)vt + (size_t)z * 64 * 1024 * 2;

  // ---- stage Q (32 rows x 128 B) ----
  {
    int o = tid * 16;
    int row = o >> 7, ch = (o >> 4) & 7;
    gload16(Qb + (size_t)row * 2048 + ((ch ^ (row & 7)) << 4), (char*)lQ + o);
  }
  // ---- stage K chunk 0 ----
#pragma unroll
  for (int it = 0; it < 4; ++it) {
    int o = tid * 16 + it * 4096;
    int row = o >> 7, ch = (o >> 4) & 7;
    gload16(Kb + (size_t)row * 2048 + ((ch ^ (row & 7)) << 4), (char*)lK[0] + o);
  }
  __syncthreads();

  // Q fragments (rows ii*16+lr, k = ks*32 + kg*8)
  bf16x8 qf[2][2];
#pragma unroll
  for (int ii = 0; ii < 2; ++ii)
#pragma unroll
    for (int ks = 0; ks < 2; ++ks) {
      int ra = ii * 16 + lr;
      int cc = ks * 4 + kg;
      qf[ii][ks] = *(const bf16x8*)((const char*)lQ + ra * 128 + ((cc ^ (ra & 7)) << 4));
    }

  f32x4 accS[8][2][2] = {};
#pragma unroll
  for (int c = 0; c < 8; ++c) {
    if (c < 7) {
#pragma unroll
      for (int it = 0; it < 4; ++it) {
        int o = tid * 16 + it * 4096;
        int row = o >> 7, ch = (o >> 4) & 7;
        gload16(Kb + (size_t)((c + 1) * 128 + row) * 2048 + ((ch ^ (row & 7)) << 4),
                (char*)lK[(c + 1) & 1] + o);
      }
    }
#pragma unroll
    for (int ks = 0; ks < 2; ++ks) {
      bf16x8 bvf[2];
#pragma unroll
      for (int jj = 0; jj < 2; ++jj) {
        int rb = wid * 32 + jj * 16 + lr;
        int cc = ks * 4 + kg;
        bvf[jj] = *(const bf16x8*)((const char*)lK[c & 1] + rb * 128 + ((cc ^ (rb & 7)) << 4));
      }
#pragma unroll
      for (int ii = 0; ii < 2; ++ii)
#pragma unroll
        for (int jj = 0; jj < 2; ++jj)
          accS[c][ii][jj] =
              __builtin_amdgcn_mfma_f32_16x16x32_bf16(qf[ii][ks], bvf[jj], accS[c][ii][jj], 0, 0, 0);
    }
    __syncthreads();
  }

  // ---- prefetch V chunk 0 under softmax ----
#pragma unroll
  for (int it = 0; it < 4; ++it) {
    int o = tid * 16 + it * 4096;
    int row = o >> 8, ch = (o >> 4) & 15;
    gload16(Vb + (size_t)row * 2048 + ((ch ^ (row & 15)) << 4), (char*)lV[0] + o);
  }

  // ---- softmax: scale, row-max ----
  float rmax[2][4];
#pragma unroll
  for (int ii = 0; ii < 2; ++ii)
#pragma unroll
    for (int r = 0; r < 4; ++r) rmax[ii][r] = -1e30f;
#pragma unroll
  for (int c = 0; c < 8; ++c)
#pragma unroll
    for (int ii = 0; ii < 2; ++ii)
#pragma unroll
      for (int jj = 0; jj < 2; ++jj)
#pragma unroll
        for (int r = 0; r < 4; ++r) {
          float v = accS[c][ii][jj][r] * 0.125f;
          accS[c][ii][jj][r] = v;
          rmax[ii][r] = fmaxf(rmax[ii][r], v);
        }
#pragma unroll
  for (int ii = 0; ii < 2; ++ii)
#pragma unroll
    for (int r = 0; r < 4; ++r) {
      float v = rmax[ii][r];
      v = fmaxf(v, __shfl_xor(v, 1));
      v = fmaxf(v, __shfl_xor(v, 2));
      v = fmaxf(v, __shfl_xor(v, 4));
      v = fmaxf(v, __shfl_xor(v, 8));
      rmax[ii][r] = v;
    }
  if (lr == 0) {
#pragma unroll
    for (int ii = 0; ii < 2; ++ii)
#pragma unroll
      for (int r = 0; r < 4; ++r) redM[wid][ii * 16 + kg * 4 + r] = rmax[ii][r];
  }
  __syncthreads();
  float rowm[2][4], rsum[2][4];
#pragma unroll
  for (int ii = 0; ii < 2; ++ii)
#pragma unroll
    for (int r = 0; r < 4; ++r) {
      int row = ii * 16 + kg * 4 + r;
      rowm[ii][r] = fmaxf(fmaxf(redM[0][row], redM[1][row]), fmaxf(redM[2][row], redM[3][row]));
      rsum[ii][r] = 0.f;
    }
#pragma unroll
  for (int c = 0; c < 8; ++c)
#pragma unroll
    for (int ii = 0; ii < 2; ++ii)
#pragma unroll
      for (int jj = 0; jj < 2; ++jj)
#pragma unroll
        for (int r = 0; r < 4; ++r) {
          float e = __expf(accS[c][ii][jj][r] - rowm[ii][r]);
          accS[c][ii][jj][r] = e;
          rsum[ii][r] += e;
        }
#pragma unroll
  for (int ii = 0; ii < 2; ++ii)
#pragma unroll
    for (int r = 0; r < 4; ++r) {
      float v = rsum[ii][r];
      v += __shfl_xor(v, 1);
      v += __shfl_xor(v, 2);
      v += __shfl_xor(v, 4);
      v += __shfl_xor(v, 8);
      rsum[ii][r] = v;
    }
  if (lr == 0) {
#pragma unroll
    for (int ii = 0; ii < 2; ++ii)
#pragma unroll
      for (int r = 0; r < 4; ++r) redS[wid][ii * 16 + kg * 4 + r] = rsum[ii][r];
  }
  __syncthreads();
  float inv[2][4];
#pragma unroll
  for (int ii = 0; ii < 2; ++ii)
#pragma unroll
    for (int r = 0; r < 4; ++r) {
      int row = ii * 16 + kg * 4 + r;
      inv[ii][r] = 1.0f / (redS[0][row] + redS[1][row] + redS[2][row] + redS[3][row]);
    }

  // ---- phase 3: probs write + PV ----
  const int ipv = wid >> 1, jpv = wid & 1;
  f32x4 accPV[2] = {};
  float* Pg = probs + (size_t)z * 1024 * 1024 + (size_t)m0 * 1024;

#pragma unroll
  for (int c = 0; c < 8; ++c) {
#pragma unroll
    for (int ii = 0; ii < 2; ++ii)
#pragma unroll
      for (int jj = 0; jj < 2; ++jj)
#pragma unroll
        for (int r = 0; r < 4; ++r) {
          float p = accS[c][ii][jj][r] * inv[ii][r];
          int row = ii * 16 + kg * 4 + r;
          int col = wid * 32 + jj * 16 + lr;
          Pg[(size_t)row * 1024 + c * 128 + col] = p;
          *(u16*)((char*)lP + row * 256 + ((((col >> 3) ^ (row & 15))) << 4) + (col & 7) * 2) =
              f2bf(p);
        }
    if (c < 7) {
#pragma unroll
      for (int it = 0; it < 4; ++it) {
        int o = tid * 16 + it * 4096;
        int row = o >> 8, ch = (o >> 4) & 15;
        gload16(Vb + (size_t)row * 2048 + (c + 1) * 256 + ((ch ^ (row & 15)) << 4),
                (char*)lV[(c + 1) & 1] + o);
      }
    }
    __syncthreads();
#pragma unroll
    for (int ks = 0; ks < 4; ++ks) {
      int cc = ks * 4 + kg;
      int ra = ipv * 16 + lr;
      bf16x8 pa = *(const bf16x8*)((const char*)lP + ra * 256 + ((cc ^ (ra & 15)) << 4));
#pragma unroll
      for (int jjj = 0; jjj < 2; ++jjj) {
        int rb = jpv * 32 + jjj * 16 + lr;
        bf16x8 vbf = *(const bf16x8*)((const char*)lV[c & 1] + rb * 256 + ((cc ^ (rb & 15)) << 4));
        accPV[jjj] = __builtin_amdgcn_mfma_f32_16x16x32_bf16(pa, vbf, accPV[jjj], 0, 0, 0);
      }
    }
    __syncthreads();
  }

#pragma unroll
  for (int jjj = 0; jjj < 2; ++jjj)
#pragma unroll
    for (int r = 0; r < 4; ++r) {
      int row = m0 + ipv * 16 + kg * 4 + r;
      int d = jpv * 32 + jjj * 16 + lr;
      ctx[((size_t)(b * 1024 + row)) * 1024 + h * 64 + d] = f2bf(accPV[jjj][r]);
    }
}

// ---------------------------------------------------------------------------
extern "C" void kernel_launch(void* const* d_in, const int* in_sizes, int n_in,
                              void* d_out, int out_size, void* d_ws, size_t ws_size,
                              hipStream_t stream) {
  const float* query = (const float*)d_in[0];
  const float* key_ = (const float*)d_in[1];
  const float* value = (const float*)d_in[2];
  const float* Wq = (const float*)d_in[3];
  const float* bq = (const float*)d_in[4];
  const float* Wk = (const float*)d_in[5];
  const float* bk = (const float*)d_in[6];
  const float* Wv = (const float*)d_in[7];
  const float* bv = (const float*)d_in[8];
  const float* Wo = (const float*)d_in[9];
  const float* bo = (const float*)d_in[10];

  float* out = (float*)d_out;
  float* probs = out + (size_t)4 * 1024 * 1024;

  char* w = (char*)d_ws;
  const size_t SZ_MK = (size_t)4096 * 1024 * 2;  // 8 MB bf16
  const size_t SZ_W = (size_t)1024 * 1024 * 2;   // 2 MB bf16
  u16* qin = (u16*)w; w += SZ_MK;
  u16* kin = (u16*)w; w += SZ_MK;
  u16* vin = (u16*)w; w += SZ_MK;
  u16* qr = (u16*)w; w += SZ_MK;
  u16* kr = (u16*)w; w += SZ_MK;
  u16* vb = (u16*)w; w += SZ_MK;
  u16* WqT = (u16*)w; w += SZ_W;
  u16* WkT = (u16*)w; w += SZ_W;
  u16* WvT = (u16*)w; w += SZ_W;
  u16* WoT = (u16*)w; w += SZ_W;
  float* cosT = (float*)w; w += 1024 * 32 * 4;
  float* sinT = (float*)w; w += 1024 * 32 * 4;
  // aliases (lifetimes do not overlap):
  u16* vt = kin;   // kin dead after k-projection; vt written afterwards
  u16* ctx = qin;  // qin dead after q-projection; ctx written by fused attn

  dim3 blk(256);
  hipLaunchKernelGGL(rope_tables_kernel, dim3(128), blk, 0, stream, cosT, sinT);
  hipLaunchKernelGGL(tobf16_kernel, dim3(4096), blk, 0, stream, query, qin);
  hipLaunchKernelGGL(tobf16_kernel, dim3(4096), blk, 0, stream, key_, kin);
  hipLaunchKernelGGL(tobf16_kernel, dim3(4096), blk, 0, stream, value, vin);
  dim3 wg(32, 32);
  hipLaunchKernelGGL(wtrans_kernel, wg, blk, 0, stream, Wq, WqT);
  hipLaunchKernelGGL(wtrans_kernel, wg, blk, 0, stream, Wk, WkT);
  hipLaunchKernelGGL(wtrans_kernel, wg, blk, 0, stream, Wv, WvT);
  hipLaunchKernelGGL(wtrans_kernel, wg, blk, 0, stream, Wo, WoT);

  dim3 pg(8, 32);
  hipLaunchKernelGGL(HIP_KERNEL_NAME(gemm_bias<0>), pg, blk, 0, stream,
                     qin, WqT, bq, (void*)qr, cosT, sinT, 4096, 1024, 1024);
  hipLaunchKernelGGL(HIP_KERNEL_NAME(gemm_bias<0>), pg, blk, 0, stream,
                     kin, WkT, bk, (void*)kr, cosT, sinT, 4096, 1024, 1024);
  hipLaunchKernelGGL(HIP_KERNEL_NAME(gemm_bias<1>), pg, blk, 0, stream,
                     vin, WvT, bv, (void*)vb, cosT, sinT, 4096, 1024, 1024);
  hipLaunchKernelGGL(vtrans_kernel, dim3(16, 64), blk, 0, stream, vb, vt);

  hipLaunchKernelGGL(fused_attn_kernel, dim3(32, 64), blk, 0, stream,
                     qr, kr, vt, probs, ctx);
  hipLaunchKernelGGL(HIP_KERNEL_NAME(gemm_bias<2>), pg, blk, 0, stream,
                     ctx, WoT, bo, (void*)out, cosT, sinT, 4096, 1024, 1024);
}

// Round 3
// 190.206 us; speedup vs baseline: 1.9227x; 1.2741x over previous
//
#include <hip/hip_runtime.h>
#include <hip/hip_bf16.h>

typedef __attribute__((ext_vector_type(8))) short bf16x8;
typedef __attribute__((ext_vector_type(4))) float f32x4;
typedef unsigned short u16;

__device__ __forceinline__ u16 f2bf(float f) {
  unsigned u = __float_as_uint(f);
  u += 0x7fffu + ((u >> 16) & 1u);
  return (u16)(u >> 16);
}

__device__ __forceinline__ void gload16(const void* g, void* l) {
  __builtin_amdgcn_global_load_lds(
      (const __attribute__((address_space(1))) unsigned int*)g,
      (__attribute__((address_space(3))) unsigned int*)l, 16, 0, 0);
}

// ---------------- merged prep: tobf16 x3, wtrans x4, rope tables -----------
// grid (4096, 5): z<3 -> convert tensor z; z==3 -> transpose 4 weights;
// z==4 -> rope tables (first 128 blocks).
__global__ __launch_bounds__(256) void prep_kernel(
    const float* __restrict__ query, const float* __restrict__ key_,
    const float* __restrict__ value, u16* __restrict__ qin,
    u16* __restrict__ kin, u16* __restrict__ vin,
    const float* __restrict__ Wq, const float* __restrict__ Wk,
    const float* __restrict__ Wv, const float* __restrict__ Wo,
    u16* __restrict__ WqT, u16* __restrict__ WkT, u16* __restrict__ WvT,
    u16* __restrict__ WoT, float* __restrict__ cosT, float* __restrict__ sinT) {
  __shared__ float tile[32][33];
  const int z = blockIdx.z;
  const int bx = blockIdx.x;
  const int tid = threadIdx.x;
  if (z < 3) {
    const float* in = z == 0 ? query : z == 1 ? key_ : value;
    u16* out = z == 0 ? qin : z == 1 ? kin : vin;
    size_t i = ((size_t)bx * 256 + tid) * 4;
    float4 v = *(const float4*)(in + i);
    ushort4 o = make_ushort4(f2bf(v.x), f2bf(v.y), f2bf(v.z), f2bf(v.w));
    *(ushort4*)(out + i) = o;
  } else if (z == 3) {
    const int w = bx >> 10;
    const float* W = w == 0 ? Wq : w == 1 ? Wk : w == 2 ? Wv : Wo;
    u16* Wt = w == 0 ? WqT : w == 1 ? WkT : w == 2 ? WvT : WoT;
    int tx = tid & 31, ty = tid >> 5;
    int k0 = ((bx >> 5) & 31) * 32, n0 = (bx & 31) * 32;
#pragma unroll
    for (int i = 0; i < 4; ++i)
      tile[ty + i * 8][tx] = W[(size_t)(k0 + ty + i * 8) * 1024 + n0 + tx];
    __syncthreads();
#pragma unroll
    for (int i = 0; i < 4; ++i)
      Wt[(size_t)(n0 + ty + i * 8) * 1024 + k0 + tx] = f2bf(tile[tx][ty + i * 8]);
  } else {
    int i = bx * 256 + tid;
    if (i >= 1024 * 32) return;
    int s = i >> 5, p = i & 31;
    double freq = exp(-9.210340371976184 * (double)(2 * p) / 64.0);
    double ang = sin((double)s * freq);
    cosT[i] = (float)cos(ang);
    sinT[i] = (float)sin(ang);
  }
}

// ---------------- vb (b,s,h,d) bf16 -> vt (b,h,d,s) bf16 -------------------
__global__ __launch_bounds__(256) void vtrans_kernel(const u16* __restrict__ vb,
                                                     u16* __restrict__ vt) {
  __shared__ u16 tile[64][72];
  int z = blockIdx.y, b = z >> 4, h = z & 15;
  int s0 = blockIdx.x * 64;
  int t = threadIdx.x;
#pragma unroll
  for (int it = 0; it < 2; ++it) {
    int idx = t + it * 256;
    int s = idx >> 3, d = (idx & 7) * 8;
    bf16x8 v = *(const bf16x8*)(vb + ((size_t)(b * 1024 + s0 + s) * 1024 + h * 64 + d));
    *(bf16x8*)&tile[s][d] = v;
  }
  __syncthreads();
#pragma unroll
  for (int it = 0; it < 2; ++it) {
    int idx = t + it * 256;
    int d = idx >> 3, sc = (idx & 7) * 8;
    bf16x8 o;
#pragma unroll
    for (int i = 0; i < 8; ++i) o[i] = (short)tile[sc + i][d];
    *(bf16x8*)(vt + ((size_t)(z * 64 + d)) * 1024 + s0 + sc) = o;
  }
}

// ---------------- merged Q/K/V projection GEMM -----------------------------
// grid (8, 32, 3). C = A(4096x1024) * Bt(1024x1024)^T + bias.
// z<2: RoPE epilogue -> bf16; z==2: plain bf16.
__global__ __launch_bounds__(256) void proj_gemm_kernel(
    const u16* __restrict__ qin, const u16* __restrict__ kin,
    const u16* __restrict__ vin, const u16* __restrict__ WqT,
    const u16* __restrict__ WkT, const u16* __restrict__ WvT,
    const float* __restrict__ bq, const float* __restrict__ bk,
    const float* __restrict__ bv, u16* __restrict__ qr, u16* __restrict__ kr,
    u16* __restrict__ vb, const float* __restrict__ cosT,
    const float* __restrict__ sinT) {
  __shared__ u16 lA[128 * 32];
  __shared__ u16 lB[128 * 32];
  const int z = blockIdx.z;
  const u16* A = z == 0 ? qin : z == 1 ? kin : vin;
  const u16* Bt = z == 0 ? WqT : z == 1 ? WkT : WvT;
  const float* bias = z == 0 ? bq : z == 1 ? bk : bv;
  u16* Cout = z == 0 ? qr : z == 1 ? kr : vb;

  const int tid = threadIdx.x;
  const int lane = tid & 63, wid = tid >> 6;
  const int wm = wid >> 1, wn = wid & 1;
  const int lr = lane & 15, kg = lane >> 4;
  const int m0 = blockIdx.y * 128, n0 = blockIdx.x * 128;

  f32x4 acc[4][4] = {};
  for (int k0 = 0; k0 < 1024; k0 += 32) {
#pragma unroll
    for (int it = 0; it < 2; ++it) {
      int o = tid * 16 + it * 4096;
      int row = o >> 6;
      int cbs = (((o >> 4) & 3) ^ (row & 3)) << 4;  // chunk swizzle
      gload16((const char*)A + ((size_t)(m0 + row) * 1024 + k0) * 2 + cbs, (char*)lA + o);
      gload16((const char*)Bt + ((size_t)(n0 + row) * 1024 + k0) * 2 + cbs, (char*)lB + o);
    }
    __syncthreads();
    bf16x8 av[4], bv_[4];
#pragma unroll
    for (int i = 0; i < 4; ++i) {
      int ra = wm * 64 + i * 16 + lr;
      av[i] = *(const bf16x8*)((const char*)lA + ra * 64 + ((kg ^ (ra & 3)) << 4));
      int rb = wn * 64 + i * 16 + lr;
      bv_[i] = *(const bf16x8*)((const char*)lB + rb * 64 + ((kg ^ (rb & 3)) << 4));
    }
#pragma unroll
    for (int i = 0; i < 4; ++i)
#pragma unroll
      for (int j = 0; j < 4; ++j)
        acc[i][j] = __builtin_amdgcn_mfma_f32_16x16x32_bf16(av[i], bv_[j], acc[i][j], 0, 0, 0);
    __syncthreads();
  }
#pragma unroll
  for (int i = 0; i < 4; ++i) {
#pragma unroll
    for (int j = 0; j < 4; ++j) {
      int col = n0 + wn * 64 + j * 16 + lr;
      float bcol = bias[col];
#pragma unroll
      for (int r = 0; r < 4; ++r) {
        int row = m0 + wm * 64 + i * 16 + kg * 4 + r;
        float v = acc[i][j][r] + bcol;
        if (z == 2) {
          Cout[(size_t)row * 1024 + col] = f2bf(v);
        } else {
          float pv = __shfl_xor(v, 1);
          int p = (col & 63) >> 1;
          int s = row & 1023;
          float ct = cosT[s * 32 + p], st = sinT[s * 32 + p];
          float ov = (col & 1) ? (v * ct + pv * st) : (v * ct - pv * st);
          Cout[(size_t)row * 1024 + col] = f2bf(ov);
        }
      }
    }
  }
}

// ---------------- final output GEMM: out = ctx * WoT^T + bo (f32) ----------
__global__ __launch_bounds__(256) void out_gemm_kernel(
    const u16* __restrict__ A, const u16* __restrict__ Bt,
    const float* __restrict__ bias, float* __restrict__ Cout) {
  __shared__ u16 lA[128 * 32];
  __shared__ u16 lB[128 * 32];
  const int tid = threadIdx.x;
  const int lane = tid & 63, wid = tid >> 6;
  const int wm = wid >> 1, wn = wid & 1;
  const int lr = lane & 15, kg = lane >> 4;
  const int m0 = blockIdx.y * 128, n0 = blockIdx.x * 128;

  f32x4 acc[4][4] = {};
  for (int k0 = 0; k0 < 1024; k0 += 32) {
#pragma unroll
    for (int it = 0; it < 2; ++it) {
      int o = tid * 16 + it * 4096;
      int row = o >> 6;
      int cbs = (((o >> 4) & 3) ^ (row & 3)) << 4;
      gload16((const char*)A + ((size_t)(m0 + row) * 1024 + k0) * 2 + cbs, (char*)lA + o);
      gload16((const char*)Bt + ((size_t)(n0 + row) * 1024 + k0) * 2 + cbs, (char*)lB + o);
    }
    __syncthreads();
    bf16x8 av[4], bv_[4];
#pragma unroll
    for (int i = 0; i < 4; ++i) {
      int ra = wm * 64 + i * 16 + lr;
      av[i] = *(const bf16x8*)((const char*)lA + ra * 64 + ((kg ^ (ra & 3)) << 4));
      int rb = wn * 64 + i * 16 + lr;
      bv_[i] = *(const bf16x8*)((const char*)lB + rb * 64 + ((kg ^ (rb & 3)) << 4));
    }
#pragma unroll
    for (int i = 0; i < 4; ++i)
#pragma unroll
      for (int j = 0; j < 4; ++j)
        acc[i][j] = __builtin_amdgcn_mfma_f32_16x16x32_bf16(av[i], bv_[j], acc[i][j], 0, 0, 0);
    __syncthreads();
  }
#pragma unroll
  for (int i = 0; i < 4; ++i)
#pragma unroll
    for (int j = 0; j < 4; ++j) {
      int col = n0 + wn * 64 + j * 16 + lr;
      float bcol = bias[col];
#pragma unroll
      for (int r = 0; r < 4; ++r) {
        int row = m0 + wm * 64 + i * 16 + kg * 4 + r;
        Cout[(size_t)row * 1024 + col] = acc[i][j][r] + bcol;
      }
    }
}

// ---------------- fused scores + softmax + PV ------------------------------
__global__ __launch_bounds__(256, 2) void fused_attn_kernel(
    const u16* __restrict__ qr, const u16* __restrict__ kr,
    const u16* __restrict__ vt, float* __restrict__ probs,
    u16* __restrict__ ctx) {
  __shared__ u16 lQ[32 * 64];
  __shared__ u16 lK[2][128 * 64];
  __shared__ u16 lV[2][64 * 128];
  __shared__ u16 lP[32 * 128];
  __shared__ float redM[4][32];
  __shared__ float redS[4][32];

  const int tid = threadIdx.x;
  const int lane = tid & 63, wid = tid >> 6;
  const int lr = lane & 15, kg = lane >> 4;
  const int z = blockIdx.y, b = z >> 4, h = z & 15;
  const int m0 = blockIdx.x * 32;

  const char* Qb = (const char*)qr + ((size_t)(b * 1024 + m0) * 1024 + h * 64) * 2;
  const char* Kb = (const char*)kr + ((size_t)(b * 1024) * 1024 + h * 64) * 2;
  const char* Vb = (const char*)vt + (size_t)z * 64 * 1024 * 2;

  {
    int o = tid * 16;
    int row = o >> 7, ch = (o >> 4) & 7;
    gload16(Qb + (size_t)row * 2048 + ((ch ^ (row & 7)) << 4), (char*)lQ + o);
  }
#pragma unroll
  for (int it = 0; it < 4; ++it) {
    int o = tid * 16 + it * 4096;
    int row = o >> 7, ch = (o >> 4) & 7;
    gload16(Kb + (size_t)row * 2048 + ((ch ^ (row & 7)) << 4), (char*)lK[0] + o);
  }
  __syncthreads();

  bf16x8 qf[2][2];
#pragma unroll
  for (int ii = 0; ii < 2; ++ii)
#pragma unroll
    for (int ks = 0; ks < 2; ++ks) {
      int ra = ii * 16 + lr;
      int cc = ks * 4 + kg;
      qf[ii][ks] = *(const bf16x8*)((const char*)lQ + ra * 128 + ((cc ^ (ra & 7)) << 4));
    }

  f32x4 accS[8][2][2] = {};
#pragma unroll
  for (int c = 0; c < 8; ++c) {
    if (c < 7) {
#pragma unroll
      for (int it = 0; it < 4; ++it) {
        int o = tid * 16 + it * 4096;
        int row = o >> 7, ch = (o >> 4) & 7;
        gload16(Kb + (size_t)((c + 1) * 128 + row) * 2048 + ((ch ^ (row & 7)) << 4),
                (char*)lK[(c + 1) & 1] + o);
      }
    }
#pragma unroll
    for (int ks = 0; ks < 2; ++ks) {
      bf16x8 bvf[2];
#pragma unroll
      for (int jj = 0; jj < 2; ++jj) {
        int rb = wid * 32 + jj * 16 + lr;
        int cc = ks * 4 + kg;
        bvf[jj] = *(const bf16x8*)((const char*)lK[c & 1] + rb * 128 + ((cc ^ (rb & 7)) << 4));
      }
#pragma unroll
      for (int ii = 0; ii < 2; ++ii)
#pragma unroll
        for (int jj = 0; jj < 2; ++jj)
          accS[c][ii][jj] =
              __builtin_amdgcn_mfma_f32_16x16x32_bf16(qf[ii][ks], bvf[jj], accS[c][ii][jj], 0, 0, 0);
    }
    __syncthreads();
  }

#pragma unroll
  for (int it = 0; it < 4; ++it) {
    int o = tid * 16 + it * 4096;
    int row = o >> 8, ch = (o >> 4) & 15;
    gload16(Vb + (size_t)row * 2048 + ((ch ^ (row & 15)) << 4), (char*)lV[0] + o);
  }

  float rmax[2][4];
#pragma unroll
  for (int ii = 0; ii < 2; ++ii)
#pragma unroll
    for (int r = 0; r < 4; ++r) rmax[ii][r] = -1e30f;
#pragma unroll
  for (int c = 0; c < 8; ++c)
#pragma unroll
    for (int ii = 0; ii < 2; ++ii)
#pragma unroll
      for (int jj = 0; jj < 2; ++jj)
#pragma unroll
        for (int r = 0; r < 4; ++r) {
          float v = accS[c][ii][jj][r] * 0.125f;
          accS[c][ii][jj][r] = v;
          rmax[ii][r] = fmaxf(rmax[ii][r], v);
        }
#pragma unroll
  for (int ii = 0; ii < 2; ++ii)
#pragma unroll
    for (int r = 0; r < 4; ++r) {
      float v = rmax[ii][r];
      v = fmaxf(v, __shfl_xor(v, 1));
      v = fmaxf(v, __shfl_xor(v, 2));
      v = fmaxf(v, __shfl_xor(v, 4));
      v = fmaxf(v, __shfl_xor(v, 8));
      rmax[ii][r] = v;
    }
  if (lr == 0) {
#pragma unroll
    for (int ii = 0; ii < 2; ++ii)
#pragma unroll
      for (int r = 0; r < 4; ++r) redM[wid][ii * 16 + kg * 4 + r] = rmax[ii][r];
  }
  __syncthreads();
  float rowm[2][4], rsum[2][4];
#pragma unroll
  for (int ii = 0; ii < 2; ++ii)
#pragma unroll
    for (int r = 0; r < 4; ++r) {
      int row = ii * 16 + kg * 4 + r;
      rowm[ii][r] = fmaxf(fmaxf(redM[0][row], redM[1][row]), fmaxf(redM[2][row], redM[3][row]));
      rsum[ii][r] = 0.f;
    }
#pragma unroll
  for (int c = 0; c < 8; ++c)
#pragma unroll
    for (int ii = 0; ii < 2; ++ii)
#pragma unroll
      for (int jj = 0; jj < 2; ++jj)
#pragma unroll
        for (int r = 0; r < 4; ++r) {
          float e = __expf(accS[c][ii][jj][r] - rowm[ii][r]);
          accS[c][ii][jj][r] = e;
          rsum[ii][r] += e;
        }
#pragma unroll
  for (int ii = 0; ii < 2; ++ii)
#pragma unroll
    for (int r = 0; r < 4; ++r) {
      float v = rsum[ii][r];
      v += __shfl_xor(v, 1);
      v += __shfl_xor(v, 2);
      v += __shfl_xor(v, 4);
      v += __shfl_xor(v, 8);
      rsum[ii][r] = v;
    }
  if (lr == 0) {
#pragma unroll
    for (int ii = 0; ii < 2; ++ii)
#pragma unroll
      for (int r = 0; r < 4; ++r) redS[wid][ii * 16 + kg * 4 + r] = rsum[ii][r];
  }
  __syncthreads();
  float inv[2][4];
#pragma unroll
  for (int ii = 0; ii < 2; ++ii)
#pragma unroll
    for (int r = 0; r < 4; ++r) {
      int row = ii * 16 + kg * 4 + r;
      inv[ii][r] = 1.0f / (redS[0][row] + redS[1][row] + redS[2][row] + redS[3][row]);
    }

  const int ipv = wid >> 1, jpv = wid & 1;
  f32x4 accPV[2] = {};
  float* Pg = probs + (size_t)z * 1024 * 1024 + (size_t)m0 * 1024;

#pragma unroll
  for (int c = 0; c < 8; ++c) {
#pragma unroll
    for (int ii = 0; ii < 2; ++ii)
#pragma unroll
      for (int jj = 0; jj < 2; ++jj)
#pragma unroll
        for (int r = 0; r < 4; ++r) {
          float p = accS[c][ii][jj][r] * inv[ii][r];
          int row = ii * 16 + kg * 4 + r;
          int col = wid * 32 + jj * 16 + lr;
          Pg[(size_t)row * 1024 + c * 128 + col] = p;
          *(u16*)((char*)lP + row * 256 + ((((col >> 3) ^ (row & 15))) << 4) + (col & 7) * 2) =
              f2bf(p);
        }
    if (c < 7) {
#pragma unroll
      for (int it = 0; it < 4; ++it) {
        int o = tid * 16 + it * 4096;
        int row = o >> 8, ch = (o >> 4) & 15;
        gload16(Vb + (size_t)row * 2048 + (c + 1) * 256 + ((ch ^ (row & 15)) << 4),
                (char*)lV[(c + 1) & 1] + o);
      }
    }
    __syncthreads();
#pragma unroll
    for (int ks = 0; ks < 4; ++ks) {
      int cc = ks * 4 + kg;
      int ra = ipv * 16 + lr;
      bf16x8 pa = *(const bf16x8*)((const char*)lP + ra * 256 + ((cc ^ (ra & 15)) << 4));
#pragma unroll
      for (int jjj = 0; jjj < 2; ++jjj) {
        int rb = jpv * 32 + jjj * 16 + lr;
        bf16x8 vbf = *(const bf16x8*)((const char*)lV[c & 1] + rb * 256 + ((cc ^ (rb & 15)) << 4));
        accPV[jjj] = __builtin_amdgcn_mfma_f32_16x16x32_bf16(pa, vbf, accPV[jjj], 0, 0, 0);
      }
    }
    __syncthreads();
  }

#pragma unroll
  for (int jjj = 0; jjj < 2; ++jjj)
#pragma unroll
    for (int r = 0; r < 4; ++r) {
      int row = m0 + ipv * 16 + kg * 4 + r;
      int d = jpv * 32 + jjj * 16 + lr;
      ctx[((size_t)(b * 1024 + row)) * 1024 + h * 64 + d] = f2bf(accPV[jjj][r]);
    }
}

// ---------------------------------------------------------------------------
extern "C" void kernel_launch(void* const* d_in, const int* in_sizes, int n_in,
                              void* d_out, int out_size, void* d_ws, size_t ws_size,
                              hipStream_t stream) {
  const float* query = (const float*)d_in[0];
  const float* key_ = (const float*)d_in[1];
  const float* value = (const float*)d_in[2];
  const float* Wq = (const float*)d_in[3];
  const float* bq = (const float*)d_in[4];
  const float* Wk = (const float*)d_in[5];
  const float* bk = (const float*)d_in[6];
  const float* Wv = (const float*)d_in[7];
  const float* bv = (const float*)d_in[8];
  const float* Wo = (const float*)d_in[9];
  const float* bo = (const float*)d_in[10];

  float* out = (float*)d_out;
  float* probs = out + (size_t)4 * 1024 * 1024;

  char* w = (char*)d_ws;
  const size_t SZ_MK = (size_t)4096 * 1024 * 2;  // 8 MB bf16
  const size_t SZ_W = (size_t)1024 * 1024 * 2;   // 2 MB bf16
  u16* qin = (u16*)w; w += SZ_MK;
  u16* kin = (u16*)w; w += SZ_MK;
  u16* vin = (u16*)w; w += SZ_MK;
  u16* qr = (u16*)w; w += SZ_MK;
  u16* kr = (u16*)w; w += SZ_MK;
  u16* vb = (u16*)w; w += SZ_MK;
  u16* WqT = (u16*)w; w += SZ_W;
  u16* WkT = (u16*)w; w += SZ_W;
  u16* WvT = (u16*)w; w += SZ_W;
  u16* WoT = (u16*)w; w += SZ_W;
  float* cosT = (float*)w; w += 1024 * 32 * 4;
  float* sinT = (float*)w; w += 1024 * 32 * 4;
  u16* vt = kin;   // kin dead after k-projection; vt written afterwards
  u16* ctx = qin;  // qin dead after q-projection; ctx written by fused attn

  dim3 blk(256);
  hipLaunchKernelGGL(prep_kernel, dim3(4096, 1, 5), blk, 0, stream,
                     query, key_, value, qin, kin, vin, Wq, Wk, Wv, Wo,
                     WqT, WkT, WvT, WoT, cosT, sinT);
  hipLaunchKernelGGL(proj_gemm_kernel, dim3(8, 32, 3), blk, 0, stream,
                     qin, kin, vin, WqT, WkT, WvT, bq, bk, bv, qr, kr, vb,
                     cosT, sinT);
  hipLaunchKernelGGL(vtrans_kernel, dim3(16, 64), blk, 0, stream, vb, vt);
  hipLaunchKernelGGL(fused_attn_kernel, dim3(32, 64), blk, 0, stream,
                     qr, kr, vt, probs, ctx);
  hipLaunchKernelGGL(out_gemm_kernel, dim3(8, 32), blk, 0, stream,
                     ctx, WoT, bo, out);
}

// Round 4
// 189.144 us; speedup vs baseline: 1.9335x; 1.0056x over previous
//
#include <hip/hip_runtime.h>
#include <hip/hip_bf16.h>

typedef __attribute__((ext_vector_type(8))) short bf16x8;
typedef __attribute__((ext_vector_type(4))) float f32x4;
typedef unsigned short u16;

__device__ __forceinline__ u16 f2bf(float f) {
  unsigned u = __float_as_uint(f);
  u += 0x7fffu + ((u >> 16) & 1u);
  return (u16)(u >> 16);
}

__device__ __forceinline__ void gload16(const void* g, void* l) {
  __builtin_amdgcn_global_load_lds(
      (const __attribute__((address_space(1))) unsigned int*)g,
      (__attribute__((address_space(3))) unsigned int*)l, 16, 0, 0);
}

// raw workgroup barrier WITHOUT implicit vmcnt(0) drain; memory clobbers
// keep the compiler from moving LDS accesses across it.
__device__ __forceinline__ void blockbar() {
  asm volatile("" ::: "memory");
  __builtin_amdgcn_s_barrier();
  asm volatile("" ::: "memory");
}

// ---------------- merged prep: tobf16 x3, wtrans x4, rope tables -----------
__global__ __launch_bounds__(256) void prep_kernel(
    const float* __restrict__ query, const float* __restrict__ key_,
    const float* __restrict__ value, u16* __restrict__ qin,
    u16* __restrict__ kin, u16* __restrict__ vin,
    const float* __restrict__ Wq, const float* __restrict__ Wk,
    const float* __restrict__ Wv, const float* __restrict__ Wo,
    u16* __restrict__ WqT, u16* __restrict__ WkT, u16* __restrict__ WvT,
    u16* __restrict__ WoT, float* __restrict__ cosT, float* __restrict__ sinT) {
  __shared__ float tile[32][33];
  const int z = blockIdx.z;
  const int bx = blockIdx.x;
  const int tid = threadIdx.x;
  if (z < 3) {
    const float* in = z == 0 ? query : z == 1 ? key_ : value;
    u16* out = z == 0 ? qin : z == 1 ? kin : vin;
    size_t i = ((size_t)bx * 256 + tid) * 4;
    float4 v = *(const float4*)(in + i);
    ushort4 o = make_ushort4(f2bf(v.x), f2bf(v.y), f2bf(v.z), f2bf(v.w));
    *(ushort4*)(out + i) = o;
  } else if (z == 3) {
    const int w = bx >> 10;
    const float* W = w == 0 ? Wq : w == 1 ? Wk : w == 2 ? Wv : Wo;
    u16* Wt = w == 0 ? WqT : w == 1 ? WkT : w == 2 ? WvT : WoT;
    int tx = tid & 31, ty = tid >> 5;
    int k0 = ((bx >> 5) & 31) * 32, n0 = (bx & 31) * 32;
#pragma unroll
    for (int i = 0; i < 4; ++i)
      tile[ty + i * 8][tx] = W[(size_t)(k0 + ty + i * 8) * 1024 + n0 + tx];
    __syncthreads();
#pragma unroll
    for (int i = 0; i < 4; ++i)
      Wt[(size_t)(n0 + ty + i * 8) * 1024 + k0 + tx] = f2bf(tile[tx][ty + i * 8]);
  } else {
    int i = bx * 256 + tid;
    if (i >= 1024 * 32) return;
    int s = i >> 5, p = i & 31;
    double freq = exp(-9.210340371976184 * (double)(2 * p) / 64.0);
    double ang = sin((double)s * freq);
    cosT[i] = (float)cos(ang);
    sinT[i] = (float)sin(ang);
  }
}

// ---------------- merged Q/K/V projection GEMM (dbuf, counted vmcnt) -------
// grid (8, 32, 3). C = A(4096x1024) * Bt(1024x1024)^T + bias.
// z<2: RoPE epilogue -> bf16 (qr/kr); z==2: direct V-transpose -> vt (b,h,d,s)
__global__ __launch_bounds__(256) void proj_gemm_kernel(
    const u16* __restrict__ qin, const u16* __restrict__ kin,
    const u16* __restrict__ vin, const u16* __restrict__ WqT,
    const u16* __restrict__ WkT, const u16* __restrict__ WvT,
    const float* __restrict__ bq, const float* __restrict__ bk,
    const float* __restrict__ bv, u16* __restrict__ qr, u16* __restrict__ kr,
    u16* __restrict__ vt, const float* __restrict__ cosT,
    const float* __restrict__ sinT) {
  __shared__ u16 lA[2][128 * 32];
  __shared__ u16 lB[2][128 * 32];
  const int z = blockIdx.z;
  const u16* A = z == 0 ? qin : z == 1 ? kin : vin;
  const u16* Bt = z == 0 ? WqT : z == 1 ? WkT : WvT;
  const float* bias = z == 0 ? bq : z == 1 ? bk : bv;

  const int tid = threadIdx.x;
  const int lane = tid & 63, wid = tid >> 6;
  const int wm = wid >> 1, wn = wid & 1;
  const int lr = lane & 15, kg = lane >> 4;
  const int m0 = blockIdx.y * 128, n0 = blockIdx.x * 128;

  // stage one 128x32 A-tile + B-tile into buffer `bu` (4 gloads/thread)
  auto stage = [&](int bu, int k0) {
#pragma unroll
    for (int it = 0; it < 2; ++it) {
      int o = tid * 16 + it * 4096;
      int row = o >> 6;
      int cbs = (((o >> 4) & 3) ^ (row & 3)) << 4;
      gload16((const char*)A + ((size_t)(m0 + row) * 1024 + k0) * 2 + cbs,
              (char*)lA[bu] + o);
      gload16((const char*)Bt + ((size_t)(n0 + row) * 1024 + k0) * 2 + cbs,
              (char*)lB[bu] + o);
    }
  };

  stage(0, 0);
  f32x4 acc[4][4] = {};
  for (int t = 0; t < 32; ++t) {
    if (t < 31) {
      stage((t + 1) & 1, (t + 1) * 32);
      asm volatile("s_waitcnt vmcnt(4)" ::: "memory");
    } else {
      asm volatile("s_waitcnt vmcnt(0)" ::: "memory");
    }
    blockbar();
    const int cb = t & 1;
    bf16x8 av[4], bv_[4];
#pragma unroll
    for (int i = 0; i < 4; ++i) {
      int ra = wm * 64 + i * 16 + lr;
      av[i] = *(const bf16x8*)((const char*)lA[cb] + ra * 64 + ((kg ^ (ra & 3)) << 4));
      int rb = wn * 64 + i * 16 + lr;
      bv_[i] = *(const bf16x8*)((const char*)lB[cb] + rb * 64 + ((kg ^ (rb & 3)) << 4));
    }
#pragma unroll
    for (int i = 0; i < 4; ++i)
#pragma unroll
      for (int j = 0; j < 4; ++j)
        acc[i][j] = __builtin_amdgcn_mfma_f32_16x16x32_bf16(av[i], bv_[j], acc[i][j], 0, 0, 0);
    blockbar();
  }

  if (z == 2) {
    // direct transpose: vt[(b*16+h)*64 + d][s] ; each lane's 4 rows are
    // contiguous in s -> one ushort4 store per fragment.
    const int bb = m0 >> 10;
#pragma unroll
    for (int i = 0; i < 4; ++i) {
      int srow = (m0 & 1023) + wm * 64 + i * 16 + kg * 4;
#pragma unroll
      for (int j = 0; j < 4; ++j) {
        int col = n0 + wn * 64 + j * 16 + lr;
        float bcol = bias[col];
        int h = col >> 6, d = col & 63;
        ushort4 o;
        o.x = f2bf(acc[i][j][0] + bcol);
        o.y = f2bf(acc[i][j][1] + bcol);
        o.z = f2bf(acc[i][j][2] + bcol);
        o.w = f2bf(acc[i][j][3] + bcol);
        *(ushort4*)(vt + ((size_t)((bb * 16 + h) * 64 + d)) * 1024 + srow) = o;
      }
    }
  } else {
    u16* Cout = z == 0 ? qr : kr;
#pragma unroll
    for (int i = 0; i < 4; ++i) {
#pragma unroll
      for (int j = 0; j < 4; ++j) {
        int col = n0 + wn * 64 + j * 16 + lr;
        float bcol = bias[col];
#pragma unroll
        for (int r = 0; r < 4; ++r) {
          int row = m0 + wm * 64 + i * 16 + kg * 4 + r;
          float v = acc[i][j][r] + bcol;
          float pv = __shfl_xor(v, 1);
          int p = (col & 63) >> 1;
          int s = row & 1023;
          float ct = cosT[s * 32 + p], st = sinT[s * 32 + p];
          float ov = (col & 1) ? (v * ct + pv * st) : (v * ct - pv * st);
          Cout[(size_t)row * 1024 + col] = f2bf(ov);
        }
      }
    }
  }
}

// ---------------- final output GEMM (dbuf, counted vmcnt), f32 out ---------
__global__ __launch_bounds__(256) void out_gemm_kernel(
    const u16* __restrict__ A, const u16* __restrict__ Bt,
    const float* __restrict__ bias, float* __restrict__ Cout) {
  __shared__ u16 lA[2][128 * 32];
  __shared__ u16 lB[2][128 * 32];
  const int tid = threadIdx.x;
  const int lane = tid & 63, wid = tid >> 6;
  const int wm = wid >> 1, wn = wid & 1;
  const int lr = lane & 15, kg = lane >> 4;
  const int m0 = blockIdx.y * 128, n0 = blockIdx.x * 128;

  auto stage = [&](int bu, int k0) {
#pragma unroll
    for (int it = 0; it < 2; ++it) {
      int o = tid * 16 + it * 4096;
      int row = o >> 6;
      int cbs = (((o >> 4) & 3) ^ (row & 3)) << 4;
      gload16((const char*)A + ((size_t)(m0 + row) * 1024 + k0) * 2 + cbs,
              (char*)lA[bu] + o);
      gload16((const char*)Bt + ((size_t)(n0 + row) * 1024 + k0) * 2 + cbs,
              (char*)lB[bu] + o);
    }
  };

  stage(0, 0);
  f32x4 acc[4][4] = {};
  for (int t = 0; t < 32; ++t) {
    if (t < 31) {
      stage((t + 1) & 1, (t + 1) * 32);
      asm volatile("s_waitcnt vmcnt(4)" ::: "memory");
    } else {
      asm volatile("s_waitcnt vmcnt(0)" ::: "memory");
    }
    blockbar();
    const int cb = t & 1;
    bf16x8 av[4], bv_[4];
#pragma unroll
    for (int i = 0; i < 4; ++i) {
      int ra = wm * 64 + i * 16 + lr;
      av[i] = *(const bf16x8*)((const char*)lA[cb] + ra * 64 + ((kg ^ (ra & 3)) << 4));
      int rb = wn * 64 + i * 16 + lr;
      bv_[i] = *(const bf16x8*)((const char*)lB[cb] + rb * 64 + ((kg ^ (rb & 3)) << 4));
    }
#pragma unroll
    for (int i = 0; i < 4; ++i)
#pragma unroll
      for (int j = 0; j < 4; ++j)
        acc[i][j] = __builtin_amdgcn_mfma_f32_16x16x32_bf16(av[i], bv_[j], acc[i][j], 0, 0, 0);
    blockbar();
  }
#pragma unroll
  for (int i = 0; i < 4; ++i)
#pragma unroll
    for (int j = 0; j < 4; ++j) {
      int col = n0 + wn * 64 + j * 16 + lr;
      float bcol = bias[col];
#pragma unroll
      for (int r = 0; r < 4; ++r) {
        int row = m0 + wm * 64 + i * 16 + kg * 4 + r;
        Cout[(size_t)row * 1024 + col] = acc[i][j][r] + bcol;
      }
    }
}

// ---------------- fused scores + softmax + PV ------------------------------
__global__ __launch_bounds__(256, 2) void fused_attn_kernel(
    const u16* __restrict__ qr, const u16* __restrict__ kr,
    const u16* __restrict__ vt, float* __restrict__ probs,
    u16* __restrict__ ctx) {
  __shared__ u16 lQ[32 * 64];
  __shared__ u16 lK[2][128 * 64];
  __shared__ u16 lV[2][64 * 128];
  __shared__ u16 lP[32 * 128];
  __shared__ float redM[4][32];
  __shared__ float redS[4][32];

  const int tid = threadIdx.x;
  const int lane = tid & 63, wid = tid >> 6;
  const int lr = lane & 15, kg = lane >> 4;
  const int z = blockIdx.y, b = z >> 4, h = z & 15;
  const int m0 = blockIdx.x * 32;

  const char* Qb = (const char*)qr + ((size_t)(b * 1024 + m0) * 1024 + h * 64) * 2;
  const char* Kb = (const char*)kr + ((size_t)(b * 1024) * 1024 + h * 64) * 2;
  const char* Vb = (const char*)vt + (size_t)z * 64 * 1024 * 2;

  auto stageK = [&](int bu, int c) {
#pragma unroll
    for (int it = 0; it < 4; ++it) {
      int o = tid * 16 + it * 4096;
      int row = o >> 7, ch = (o >> 4) & 7;
      gload16(Kb + (size_t)(c * 128 + row) * 2048 + ((ch ^ (row & 7)) << 4),
              (char*)lK[bu] + o);
    }
  };
  auto stageV = [&](int bu, int c) {
#pragma unroll
    for (int it = 0; it < 4; ++it) {
      int o = tid * 16 + it * 4096;
      int row = o >> 8, ch = (o >> 4) & 15;
      gload16(Vb + (size_t)row * 2048 + c * 256 + ((ch ^ (row & 15)) << 4),
              (char*)lV[bu] + o);
    }
  };

  // prologue: stage Q (1 load/thread) + K chunk 0
  {
    int o = tid * 16;
    int row = o >> 7, ch = (o >> 4) & 7;
    gload16(Qb + (size_t)row * 2048 + ((ch ^ (row & 7)) << 4), (char*)lQ + o);
  }
  stageK(0, 0);

  bf16x8 qf[2][2];
  f32x4 accS[8][2][2] = {};
#pragma unroll
  for (int c = 0; c < 8; ++c) {
    if (c < 7) {
      stageK((c + 1) & 1, c + 1);
      asm volatile("s_waitcnt vmcnt(4)" ::: "memory");
    } else {
      asm volatile("s_waitcnt vmcnt(0)" ::: "memory");
    }
    blockbar();
    if (c == 0) {
#pragma unroll
      for (int ii = 0; ii < 2; ++ii)
#pragma unroll
        for (int ks = 0; ks < 2; ++ks) {
          int ra = ii * 16 + lr;
          int cc = ks * 4 + kg;
          qf[ii][ks] = *(const bf16x8*)((const char*)lQ + ra * 128 + ((cc ^ (ra & 7)) << 4));
        }
    }
#pragma unroll
    for (int ks = 0; ks < 2; ++ks) {
      bf16x8 bvf[2];
#pragma unroll
      for (int jj = 0; jj < 2; ++jj) {
        int rb = wid * 32 + jj * 16 + lr;
        int cc = ks * 4 + kg;
        bvf[jj] = *(const bf16x8*)((const char*)lK[c & 1] + rb * 128 + ((cc ^ (rb & 7)) << 4));
      }
#pragma unroll
      for (int ii = 0; ii < 2; ++ii)
#pragma unroll
        for (int jj = 0; jj < 2; ++jj)
          accS[c][ii][jj] =
              __builtin_amdgcn_mfma_f32_16x16x32_bf16(qf[ii][ks], bvf[jj], accS[c][ii][jj], 0, 0, 0);
    }
    blockbar();
  }

  // prefetch V chunk 0; stays in flight across the whole softmax (lgkm-only
  // barriers below do NOT drain vmcnt).
  stageV(0, 0);

  float rmax[2][4];
#pragma unroll
  for (int ii = 0; ii < 2; ++ii)
#pragma unroll
    for (int r = 0; r < 4; ++r) rmax[ii][r] = -1e30f;
#pragma unroll
  for (int c = 0; c < 8; ++c)
#pragma unroll
    for (int ii = 0; ii < 2; ++ii)
#pragma unroll
      for (int jj = 0; jj < 2; ++jj)
#pragma unroll
        for (int r = 0; r < 4; ++r) {
          float v = accS[c][ii][jj][r] * 0.125f;
          accS[c][ii][jj][r] = v;
          rmax[ii][r] = fmaxf(rmax[ii][r], v);
        }
#pragma unroll
  for (int ii = 0; ii < 2; ++ii)
#pragma unroll
    for (int r = 0; r < 4; ++r) {
      float v = rmax[ii][r];
      v = fmaxf(v, __shfl_xor(v, 1));
      v = fmaxf(v, __shfl_xor(v, 2));
      v = fmaxf(v, __shfl_xor(v, 4));
      v = fmaxf(v, __shfl_xor(v, 8));
      rmax[ii][r] = v;
    }
  if (lr == 0) {
#pragma unroll
    for (int ii = 0; ii < 2; ++ii)
#pragma unroll
      for (int r = 0; r < 4; ++r) redM[wid][ii * 16 + kg * 4 + r] = rmax[ii][r];
  }
  asm volatile("s_waitcnt lgkmcnt(0)" ::: "memory");
  blockbar();
  float rowm[2][4], rsum[2][4];
#pragma unroll
  for (int ii = 0; ii < 2; ++ii)
#pragma unroll
    for (int r = 0; r < 4; ++r) {
      int row = ii * 16 + kg * 4 + r;
      rowm[ii][r] = fmaxf(fmaxf(redM[0][row], redM[1][row]), fmaxf(redM[2][row], redM[3][row]));
      rsum[ii][r] = 0.f;
    }
#pragma unroll
  for (int c = 0; c < 8; ++c)
#pragma unroll
    for (int ii = 0; ii < 2; ++ii)
#pragma unroll
      for (int jj = 0; jj < 2; ++jj)
#pragma unroll
        for (int r = 0; r < 4; ++r) {
          float e = __expf(accS[c][ii][jj][r] - rowm[ii][r]);
          accS[c][ii][jj][r] = e;
          rsum[ii][r] += e;
        }
#pragma unroll
  for (int ii = 0; ii < 2; ++ii)
#pragma unroll
    for (int r = 0; r < 4; ++r) {
      float v = rsum[ii][r];
      v += __shfl_xor(v, 1);
      v += __shfl_xor(v, 2);
      v += __shfl_xor(v, 4);
      v += __shfl_xor(v, 8);
      rsum[ii][r] = v;
    }
  if (lr == 0) {
#pragma unroll
    for (int ii = 0; ii < 2; ++ii)
#pragma unroll
      for (int r = 0; r < 4; ++r) redS[wid][ii * 16 + kg * 4 + r] = rsum[ii][r];
  }
  asm volatile("s_waitcnt lgkmcnt(0)" ::: "memory");
  blockbar();
  float inv[2][4];
#pragma unroll
  for (int ii = 0; ii < 2; ++ii)
#pragma unroll
    for (int r = 0; r < 4; ++r) {
      int row = ii * 16 + kg * 4 + r;
      inv[ii][r] = 1.0f / (redS[0][row] + redS[1][row] + redS[2][row] + redS[3][row]);
    }

  const int ipv = wid >> 1, jpv = wid & 1;
  f32x4 accPV[2] = {};
  float* Pg = probs + (size_t)z * 1024 * 1024 + (size_t)m0 * 1024;

#pragma unroll
  for (int c = 0; c < 8; ++c) {
    if (c < 7) stageV((c + 1) & 1, c + 1);
#pragma unroll
    for (int ii = 0; ii < 2; ++ii)
#pragma unroll
      for (int jj = 0; jj < 2; ++jj)
#pragma unroll
        for (int r = 0; r < 4; ++r) {
          float p = accS[c][ii][jj][r] * inv[ii][r];
          int row = ii * 16 + kg * 4 + r;
          int col = wid * 32 + jj * 16 + lr;
          Pg[(size_t)row * 1024 + c * 128 + col] = p;
          *(u16*)((char*)lP + row * 256 + ((((col >> 3) ^ (row & 15))) << 4) + (col & 7) * 2) =
              f2bf(p);
        }
    // wait: this iter's V-stage (4 loads) + this iter's 16 probs stores are
    // the 20 newest vmem ops; everything older (V chunk c, prior stores) done.
    if (c < 7)
      asm volatile("s_waitcnt vmcnt(20) lgkmcnt(0)" ::: "memory");
    else
      asm volatile("s_waitcnt vmcnt(16) lgkmcnt(0)" ::: "memory");
    blockbar();
#pragma unroll
    for (int ks = 0; ks < 4; ++ks) {
      int cc = ks * 4 + kg;
      int ra = ipv * 16 + lr;
      bf16x8 pa = *(const bf16x8*)((const char*)lP + ra * 256 + ((cc ^ (ra & 15)) << 4));
#pragma unroll
      for (int jjj = 0; jjj < 2; ++jjj) {
        int rb = jpv * 32 + jjj * 16 + lr;
        bf16x8 vbf = *(const bf16x8*)((const char*)lV[c & 1] + rb * 256 + ((cc ^ (rb & 15)) << 4));
        accPV[jjj] = __builtin_amdgcn_mfma_f32_16x16x32_bf16(pa, vbf, accPV[jjj], 0, 0, 0);
      }
    }
    blockbar();
  }

#pragma unroll
  for (int jjj = 0; jjj < 2; ++jjj)
#pragma unroll
    for (int r = 0; r < 4; ++r) {
      int row = m0 + ipv * 16 + kg * 4 + r;
      int d = jpv * 32 + jjj * 16 + lr;
      ctx[((size_t)(b * 1024 + row)) * 1024 + h * 64 + d] = f2bf(accPV[jjj][r]);
    }
}

// ---------------------------------------------------------------------------
extern "C" void kernel_launch(void* const* d_in, const int* in_sizes, int n_in,
                              void* d_out, int out_size, void* d_ws, size_t ws_size,
                              hipStream_t stream) {
  const float* query = (const float*)d_in[0];
  const float* key_ = (const float*)d_in[1];
  const float* value = (const float*)d_in[2];
  const float* Wq = (const float*)d_in[3];
  const float* bq = (const float*)d_in[4];
  const float* Wk = (const float*)d_in[5];
  const float* bk = (const float*)d_in[6];
  const float* Wv = (const float*)d_in[7];
  const float* bv = (const float*)d_in[8];
  const float* Wo = (const float*)d_in[9];
  const float* bo = (const float*)d_in[10];

  float* out = (float*)d_out;
  float* probs = out + (size_t)4 * 1024 * 1024;

  char* w = (char*)d_ws;
  const size_t SZ_MK = (size_t)4096 * 1024 * 2;  // 8 MB bf16
  const size_t SZ_W = (size_t)1024 * 1024 * 2;   // 2 MB bf16
  u16* qin = (u16*)w; w += SZ_MK;
  u16* kin = (u16*)w; w += SZ_MK;
  u16* vin = (u16*)w; w += SZ_MK;
  u16* qr = (u16*)w; w += SZ_MK;
  u16* kr = (u16*)w; w += SZ_MK;
  u16* vt = (u16*)w; w += SZ_MK;   // (b,h,d,s) written directly by proj z==2
  u16* WqT = (u16*)w; w += SZ_W;
  u16* WkT = (u16*)w; w += SZ_W;
  u16* WvT = (u16*)w; w += SZ_W;
  u16* WoT = (u16*)w; w += SZ_W;
  float* cosT = (float*)w; w += 1024 * 32 * 4;
  float* sinT = (float*)w; w += 1024 * 32 * 4;
  u16* ctx = qin;  // qin dead after q-projection; ctx written by fused attn

  dim3 blk(256);
  hipLaunchKernelGGL(prep_kernel, dim3(4096, 1, 5), blk, 0, stream,
                     query, key_, value, qin, kin, vin, Wq, Wk, Wv, Wo,
                     WqT, WkT, WvT, WoT, cosT, sinT);
  hipLaunchKernelGGL(proj_gemm_kernel, dim3(8, 32, 3), blk, 0, stream,
                     qin, kin, vin, WqT, WkT, WvT, bq, bk, bv, qr, kr, vt,
                     cosT, sinT);
  hipLaunchKernelGGL(fused_attn_kernel, dim3(32, 64), blk, 0, stream,
                     qr, kr, vt, probs, ctx);
  hipLaunchKernelGGL(out_gemm_kernel, dim3(8, 32), blk, 0, stream,
                     ctx, WoT, bo, out);
}